// Round 3
// baseline (578.724 us; speedup 1.0000x reference)
//
#include <hip/hip_runtime.h>
#include <cstdint>
#include <cstddef>

// CTC loss forward (mean over batch of loss/target_len), MI355X gfx950.
// One wave per batch (64 blocks x 64 threads), lane = CTC state s
// (S = 65; lane 63 also carries s=64 locally). Alpha kept in the log2 domain.
// Recurrence neighbors via DPP wave_shr1 (VALU latency — NOT ds_bpermute).
// Emissions gathered from global with a depth-32 register ring, fully
// unrolled so the ring lives in VGPRs and loads stay 32-deep in flight.

#define TMAX  256
#define BATCH 64
#define CNUM  8000
#define LMAX  32
#define SDIM  65
#define LOG2E 1.44269504088896340736f
#define LN2   0.69314718055994530942f
#define NEG2  (-1.0e9f * LOG2E)   // reference NEG = -1e9, in log2 domain

// gfx950 hardware base-2 transcendentals.
__device__ __forceinline__ float hexp2(float x) { return __builtin_amdgcn_exp2f(x); }
__device__ __forceinline__ float hlog2(float x) { return __builtin_amdgcn_logf(x); }

// Full-wave shift-right-by-1 via DPP (ctrl 0x138 = WAVE_SHR1, gfx9 lineage).
// bound_ctrl=true: lane 0 reads 0 — callers mask lanes 0/1 anyway.
__device__ __forceinline__ float wave_shr1(float x) {
    int r = __builtin_amdgcn_update_dpp(0, __float_as_int(x), 0x138, 0xF, 0xF, true);
    return __int_as_float(r);
}

__device__ __forceinline__ float lae3_log2(float a, float b, float c) {
    // log2(2^a + 2^b + 2^c), inputs in log2 domain
    float m = fmaxf(fmaxf(a, b), c);                 // v_max3
    float r = hexp2(a - m) + hexp2(b - m) + hexp2(c - m);
    return m + hlog2(r);
}

__global__ __launch_bounds__(64) void ctc_dp(
    const float* __restrict__ lp, const int* __restrict__ targets,
    const int* __restrict__ in_len, const int* __restrict__ tg_len,
    float* __restrict__ partial)
{
    const int b    = blockIdx.x;
    const int lane = threadIdx.x;           // state s = lane (0..63)
    const int Lb   = tg_len[b];
    const int Tb   = in_len[b];

    // Extended-target label for state s = lane; blanks (label 0) on even s.
    int  label = 0;
    bool skip  = false;
    if (lane & 1) {
        int k = lane >> 1;
        label = (k < Lb) ? targets[b * LMAX + k] : 0;
        int prev = (k >= 1) ? ((k - 1 < Lb) ? targets[b * LMAX + (k - 1)] : 0) : -1;
        skip = (label != 0) && (label != prev);
    }
    const bool use2 = skip && (lane >= 2);  // s<2 has no s-2 predecessor

    // Per-lane gather base: lp[t, b, label] = pbase[t * B*C]
    const float*  pbase   = lp + (size_t)b * CNUM + (size_t)label;
    const size_t  tstride = (size_t)BATCH * CNUM;

    // t = 0 init (alpha in log2 domain)
    float em0 = pbase[0];                   // lp[0, b, ext[lane]]
    float a   = NEG2;
    if (lane == 0)            a = em0 * LOG2E;
    if (lane == 1 && Lb > 0)  a = em0 * LOG2E;
    float a64 = NEG2;                       // state s=64 (valid on lane 63)

    const int steps  = Tb - 1;              // >= 128 per setup
    const int chunks = (steps + 31) >> 5;   // run chunks*32 steps, snapshot at t==steps

    // Prime the depth-32 prefetch ring with t = 1..32 (clamped)
    float ring[32];
    #pragma unroll
    for (int i = 0; i < 32; ++i) {
        int tl = 1 + i; if (tl > TMAX - 1) tl = TMAX - 1;
        ring[i] = pbase[(size_t)tl * tstride];
    }

    float a_res = a, a64_res = a64;
    int t = 1;
    for (int c = 0; c < chunks; ++c) {
        #pragma unroll
        for (int i = 0; i < 32; ++i, ++t) {
            float em2  = ring[i] * LOG2E;
            // blank emission for s=64 == lane 0's emission (label 0)
            float em2b = __uint_as_float(
                __builtin_amdgcn_readfirstlane(__float_as_uint(em2)));

            float am1 = wave_shr1(a);         // a[lane-1], VALU-latency DPP
            float am2 = wave_shr1(am1);       // a[lane-2]
            am1 = (lane >= 1) ? am1 : NEG2;
            float am2p = use2 ? am2 : NEG2;

            // s=64 update from OLD a64 and OLD a[63] (own value on lane 63);
            // computed on all lanes, only lane 63's result is meaningful.
            float m64  = fmaxf(a64, a);
            float r64  = hexp2(a64 - m64) + hexp2(a - m64);
            float a64n = m64 + hlog2(r64) + em2b;

            a   = lae3_log2(a, am1, am2p) + em2;
            a64 = a64n;

            bool last = (t == steps);
            a_res   = last ? a   : a_res;     // v_cndmask, off the chain
            a64_res = last ? a64 : a64_res;

            // prefetch emission for t+32 (clamped; steps past `steps` update
            // garbage that is never read — snapshot already taken)
            int tl = t + 32; if (tl > TMAX - 1) tl = TMAX - 1;
            ring[i] = pbase[(size_t)tl * tstride];
        }
    }

    // Gather final alpha across lanes via LDS, lane 0 finishes the loss.
    __shared__ float fin[SDIM];
    fin[lane] = a_res;
    if (lane == 63) fin[64] = a64_res;
    __syncthreads();

    if (lane == 0) {
        int iB = 2 * Lb;
        int iC = iB - 1; if (iC < 0) iC = 0;
        float vB = fin[iB];
        float vC = fin[iC];
        float tot2;
        if (Lb > 0) {
            float m = fmaxf(vB, vC);
            tot2 = m + hlog2(hexp2(vB - m) + hexp2(vC - m));
        } else {
            tot2 = vB;
        }
        float loss = -(tot2 * LN2);                  // back to natural log
        float sl   = (Lb > 0) ? (float)Lb : 1.0f;
        partial[b] = loss / sl;
    }
}

__global__ __launch_bounds__(64) void ctc_reduce(
    const float* __restrict__ partial, float* __restrict__ out)
{
    float v = partial[threadIdx.x];
    #pragma unroll
    for (int off = 32; off > 0; off >>= 1) v += __shfl_xor(v, off, 64);
    if (threadIdx.x == 0) out[0] = v * (1.0f / BATCH);
}

extern "C" void kernel_launch(void* const* d_in, const int* in_sizes, int n_in,
                              void* d_out, int out_size, void* d_ws, size_t ws_size,
                              hipStream_t stream) {
    const float* lp = (const float*)d_in[0];
    const int*   tg = (const int*)d_in[1];
    const int*   il = (const int*)d_in[2];
    const int*   tl = (const int*)d_in[3];
    float* partial  = (float*)d_ws;        // 64 floats; fully overwritten each call

    ctc_dp<<<dim3(BATCH), dim3(64), 0, stream>>>(lp, tg, il, tl, partial);
    ctc_reduce<<<dim3(1), dim3(64), 0, stream>>>(partial, (float*)d_out);
}